// Round 1
// baseline (311.658 us; speedup 1.0000x reference)
//
#include <hip/hip_runtime.h>
#include <stdint.h>

#define S_LEN 2048
#define HD    128
#define NKV   8
#define NQM   4
#define WIN   1024
#define QB    32
#define KTILE 32
#define KVROW (NKV * HD)        /* 1024 elements per K/V token row */
#define QROW  (NQM * NKV * HD)  /* 4096 elements per Q/out token row */

typedef __attribute__((ext_vector_type(8))) short bf16x8;
typedef __attribute__((ext_vector_type(4))) float f32x4;
typedef __attribute__((ext_vector_type(4))) int   i32x4;

__device__ __forceinline__ uint32_t f2bf(float f) {
  uint32_t x = __builtin_bit_cast(uint32_t, f);
  x += 0x7fffu + ((x >> 16) & 1u);   // RNE
  return x >> 16;
}

// load 8 consecutive "bf16-worth" elements starting at p
__device__ __forceinline__ void load8bf(const uint16_t* p, uint32_t o[4]) {
  i32x4 v = *reinterpret_cast<const i32x4*>(p);
  o[0] = (uint32_t)v[0]; o[1] = (uint32_t)v[1]; o[2] = (uint32_t)v[2]; o[3] = (uint32_t)v[3];
}
__device__ __forceinline__ void load8bf(const float* p, uint32_t o[4]) {
  float4 a = *reinterpret_cast<const float4*>(p);
  float4 b = *reinterpret_cast<const float4*>(p + 4);
  o[0] = f2bf(a.x) | (f2bf(a.y) << 16);
  o[1] = f2bf(a.z) | (f2bf(a.w) << 16);
  o[2] = f2bf(b.x) | (f2bf(b.y) << 16);
  o[3] = f2bf(b.z) | (f2bf(b.w) << 16);
}

__global__ void cvt_kernel(const float* __restrict__ in, uint16_t* __restrict__ out, int n4) {
  int i = blockIdx.x * blockDim.x + threadIdx.x;
  int stride = gridDim.x * blockDim.x;
  for (int j = i; j < n4; j += stride) {
    float4 v = reinterpret_cast<const float4*>(in)[j];
    ushort4 o;
    o.x = (uint16_t)f2bf(v.x); o.y = (uint16_t)f2bf(v.y);
    o.z = (uint16_t)f2bf(v.z); o.w = (uint16_t)f2bf(v.w);
    reinterpret_cast<ushort4*>(out)[j] = o;
  }
}

template <typename KVT>
__launch_bounds__(256, 2)
__global__ void attn_kernel(const float* __restrict__ Q,
                            const KVT* __restrict__ Ksrc,
                            const KVT* __restrict__ Vsrc,
                            const float* __restrict__ sinks,
                            float* __restrict__ out) {
  // LDS: K tile 32x128 bf16 (rows 256B, XOR-swizzled)  : 8 KB
  //      V^T tile 128 x 32 bf16 (rows 64B, swizzled)   : 8 KB
  //      P scratch, 2 KB per wave                      : 8 KB
  __shared__ __align__(16) uint8_t smem[24576];
  uint8_t* kls = smem;
  uint8_t* vls = smem + 8192;

  const int tid  = threadIdx.x;
  const int lane = tid & 63;
  const int wv   = tid >> 6;
  const int c    = lane & 15;   // "16-dim" lane coordinate
  const int g    = lane >> 4;   // lane group 0..3
  uint8_t* pls = smem + 16384 + wv * 2048;

  const int q0   = blockIdx.x * QB;
  const int kv   = blockIdx.y;
  const int b    = blockIdx.z;
  const int head = kv * NQM + wv;

  // ---------------- Q fragments (bf16, SM_SCALE folded in) ----------------
  const float SCALE = 0.08838834764831845f;  // 1/sqrt(128)
  bf16x8 qf[2][4];
  #pragma unroll
  for (int tq = 0; tq < 2; ++tq) {
    const float* qp = Q + (size_t)(b * S_LEN + q0 + tq * 16 + c) * QROW + head * HD;
    #pragma unroll
    for (int f = 0; f < 4; ++f) {
      int d0 = f * 32 + g * 8;
      float4 a = *reinterpret_cast<const float4*>(qp + d0);
      float4 bb = *reinterpret_cast<const float4*>(qp + d0 + 4);
      i32x4 t;
      t[0] = (int)(f2bf(a.x * SCALE) | (f2bf(a.y * SCALE) << 16));
      t[1] = (int)(f2bf(a.z * SCALE) | (f2bf(a.w * SCALE) << 16));
      t[2] = (int)(f2bf(bb.x * SCALE) | (f2bf(bb.y * SCALE) << 16));
      t[3] = (int)(f2bf(bb.z * SCALE) | (f2bf(bb.w * SCALE) << 16));
      qf[tq][f] = __builtin_bit_cast(bf16x8, t);
    }
  }

  // online-softmax state; sink acts as an initial column: m = sink, l = 1
  const float sinkv = sinks[head];
  float m_[2] = {sinkv, sinkv};
  float l_[2] = {1.0f, 1.0f};
  f32x4 acc[2][8];
  #pragma unroll
  for (int tq = 0; tq < 2; ++tq)
    #pragma unroll
    for (int dt = 0; dt < 8; ++dt) acc[tq][dt] = (f32x4)0.0f;

  // ---------------- staging coordinates ----------------
  // K: thread covers row kr (of 32), 32 bytes of bf16 at column byte kcB
  const int kr  = tid >> 3;
  const int kcB = (tid & 7) * 32;
  const uint32_t kw0 = (uint32_t)(kr * 256 + ((kcB)      ^ ((kr & 7) << 4)));
  const uint32_t kw1 = (uint32_t)(kr * 256 + ((kcB + 16) ^ ((kr & 7) << 4)));
  const KVT* kg = Ksrc + (size_t)(b * S_LEN) * KVROW + kv * HD + (tid & 7) * 16;
  // V: thread covers key pair {2*va, 2*va+1}, d range vd*8 .. +7
  const int va = tid >> 4;
  const int vd = tid & 15;
  const KVT* vg = Vsrc + (size_t)(b * S_LEN) * KVROW + kv * HD + vd * 8;

  int kstart = q0 - (WIN - 1);
  if (kstart < 0) kstart = 0;
  kstart &= ~(KTILE - 1);

  const float L2E = 1.4426950408889634f;

  for (int kt = kstart; kt <= q0; kt += KTILE) {
    __syncthreads();   // protect LDS from previous iteration's readers

    { // ---- stage K tile (swizzled rows) ----
      const KVT* src = kg + (size_t)(kt + kr) * KVROW;
      uint32_t t0[4], t1[4];
      load8bf(src, t0);
      load8bf(src + 8, t1);
      i32x4 w0, w1;
      w0[0]=(int)t0[0]; w0[1]=(int)t0[1]; w0[2]=(int)t0[2]; w0[3]=(int)t0[3];
      w1[0]=(int)t1[0]; w1[1]=(int)t1[1]; w1[2]=(int)t1[2]; w1[3]=(int)t1[3];
      *reinterpret_cast<i32x4*>(kls + kw0) = w0;
      *reinterpret_cast<i32x4*>(kls + kw1) = w1;
    }
    { // ---- stage V transposed: Vt[d][k], rows 64B, bank-swizzled ----
      const KVT* s0 = vg + (size_t)(kt + 2 * va) * KVROW;
      uint32_t r0[4], r1[4];
      load8bf(s0, r0);
      load8bf(s0 + KVROW, r1);
      #pragma unroll
      for (int i = 0; i < 8; ++i) {
        int d = vd * 8 + i;
        uint32_t lo = (i & 1) ? (r0[i >> 1] >> 16) : (r0[i >> 1] & 0xffffu);
        uint32_t hi = (i & 1) ? (r1[i >> 1] >> 16) : (r1[i >> 1] & 0xffffu);
        uint32_t byte = (uint32_t)(d * 64 + va * 4) ^ ((((uint32_t)d >> 3) & 15u) << 3);
        *reinterpret_cast<uint32_t*>(vls + byte) = lo | (hi << 16);
      }
    }
    __syncthreads();

    // ---- QK^T (swapped: St[key][q]) ----
    f32x4 st[2][2];
    #pragma unroll
    for (int a_ = 0; a_ < 2; ++a_)
      #pragma unroll
      for (int b_ = 0; b_ < 2; ++b_) st[a_][b_] = (f32x4)0.0f;

    #pragma unroll
    for (int kt_ = 0; kt_ < 2; ++kt_) {
      bf16x8 kf[4];
      #pragma unroll
      for (int f = 0; f < 4; ++f) {
        int row = kt_ * 16 + c;
        uint32_t byte = (uint32_t)(row * 256 + ((f * 64 + g * 16) ^ ((row & 7) << 4)));
        kf[f] = *reinterpret_cast<const bf16x8*>(kls + byte);
      }
      #pragma unroll
      for (int tq = 0; tq < 2; ++tq)
        #pragma unroll
        for (int f = 0; f < 4; ++f)
          st[kt_][tq] = __builtin_amdgcn_mfma_f32_16x16x32_bf16(kf[f], qf[tq][f], st[kt_][tq], 0, 0, 0);
    }

    // ---- mask (edge tiles only; wave-uniform branch) ----
    const bool need_mask = (kt + KTILE - 1 > q0) || (kt < q0 + QB - WIN);
    if (need_mask) {
      #pragma unroll
      for (int kt_ = 0; kt_ < 2; ++kt_)
        #pragma unroll
        for (int tq = 0; tq < 2; ++tq)
          #pragma unroll
          for (int r = 0; r < 4; ++r) {
            int k_ = kt + kt_ * 16 + g * 4 + r;
            int q_ = q0 + tq * 16 + c;
            bool ok = (k_ <= q_) && (k_ > q_ - WIN);
            if (!ok) st[kt_][tq][r] = -1e38f;
          }
    }

    // ---- online softmax (row = q = lane&15) + P->LDS + O rescale ----
    #pragma unroll
    for (int tq = 0; tq < 2; ++tq) {
      float vmax = fmaxf(fmaxf(fmaxf(st[0][tq][0], st[0][tq][1]), fmaxf(st[0][tq][2], st[0][tq][3])),
                         fmaxf(fmaxf(st[1][tq][0], st[1][tq][1]), fmaxf(st[1][tq][2], st[1][tq][3])));
      vmax = fmaxf(vmax, __shfl_xor(vmax, 16));
      vmax = fmaxf(vmax, __shfl_xor(vmax, 32));
      float mold = m_[tq];
      float mnew = fmaxf(mold, vmax);
      float scl  = exp2f((mold - mnew) * L2E);
      float p[2][4];
      float s = 0.0f;
      #pragma unroll
      for (int kt_ = 0; kt_ < 2; ++kt_)
        #pragma unroll
        for (int r = 0; r < 4; ++r) {
          float e = exp2f((st[kt_][tq][r] - mnew) * L2E);
          p[kt_][r] = e;
          s += e;
        }
      s += __shfl_xor(s, 16);
      s += __shfl_xor(s, 32);
      l_[tq] = l_[tq] * scl + s;
      m_[tq] = mnew;
      // pack P (bf16) into per-wave LDS: P[q][k], rows 64B
      #pragma unroll
      for (int kt_ = 0; kt_ < 2; ++kt_) {
        uint32_t lo = f2bf(p[kt_][0]) | (f2bf(p[kt_][1]) << 16);
        uint32_t hi = f2bf(p[kt_][2]) | (f2bf(p[kt_][3]) << 16);
        uint32_t byte = (uint32_t)((tq * 16 + c) * 64 + kt_ * 32 + g * 8);
        uint2 pk; pk.x = lo; pk.y = hi;
        *reinterpret_cast<uint2*>(pls + byte) = pk;
      }
      // O rescale: broadcast scale of q' = g*4+r to the acc layout
      float sc[4];
      #pragma unroll
      for (int r = 0; r < 4; ++r) sc[r] = __shfl(scl, (lane & 48) | (g * 4 + r));
      #pragma unroll
      for (int dt = 0; dt < 8; ++dt)
        #pragma unroll
        for (int r = 0; r < 4; ++r) acc[tq][dt][r] *= sc[r];
    }

    // ---- PV ----
    bf16x8 pa[2];
    #pragma unroll
    for (int tq = 0; tq < 2; ++tq)
      pa[tq] = *reinterpret_cast<const bf16x8*>(pls + (tq * 16 + c) * 64 + g * 16);
    #pragma unroll
    for (int dt = 0; dt < 8; ++dt) {
      int d = dt * 16 + c;
      uint32_t base = (uint32_t)(d * 64 + g * 16);
      uint32_t swz = (((uint32_t)d >> 3) & 15u) << 3;
      uint2 lo = *reinterpret_cast<const uint2*>(vls + ((base) ^ swz));
      uint2 hi = *reinterpret_cast<const uint2*>(vls + ((base + 8) ^ swz));
      i32x4 vv; vv[0] = (int)lo.x; vv[1] = (int)lo.y; vv[2] = (int)hi.x; vv[3] = (int)hi.y;
      bf16x8 vf = __builtin_bit_cast(bf16x8, vv);
      #pragma unroll
      for (int tq = 0; tq < 2; ++tq)
        acc[tq][dt] = __builtin_amdgcn_mfma_f32_16x16x32_bf16(pa[tq], vf, acc[tq][dt], 0, 0, 0);
    }
  }

  // ---------------- epilogue: O /= l, store ----------------
  #pragma unroll
  for (int tq = 0; tq < 2; ++tq) {
    float linv = 1.0f / l_[tq];
    float li[4];
    #pragma unroll
    for (int r = 0; r < 4; ++r) li[r] = __shfl(linv, (lane & 48) | (g * 4 + r));
    #pragma unroll
    for (int dt = 0; dt < 8; ++dt)
      #pragma unroll
      for (int r = 0; r < 4; ++r) {
        size_t o = (size_t)(b * S_LEN + q0 + tq * 16 + g * 4 + r) * QROW + head * HD + dt * 16 + c;
        out[o] = acc[tq][dt][r] * li[r];
      }
  }
}

extern "C" void kernel_launch(void* const* d_in, const int* in_sizes, int n_in,
                              void* d_out, int out_size, void* d_ws, size_t ws_size,
                              hipStream_t stream) {
  const float* Q     = (const float*)d_in[0];
  const float* K     = (const float*)d_in[1];
  const float* V     = (const float*)d_in[2];
  const float* sinks = (const float*)d_in[3];
  float* out = (float*)d_out;

  const int nK = in_sizes[1];                       // B*S*NKV*HD
  const int B  = in_sizes[0] / (S_LEN * QROW);
  dim3 grid(S_LEN / QB, NKV, B);

  const size_t need = (size_t)nK * 2u * 2u;         // Kbf + Vbf in bf16
  if (ws_size >= need) {
    uint16_t* Kb = (uint16_t*)d_ws;
    uint16_t* Vb = Kb + nK;
    cvt_kernel<<<1024, 256, 0, stream>>>(K, Kb, nK / 4);
    cvt_kernel<<<1024, 256, 0, stream>>>(V, Vb, nK / 4);
    attn_kernel<uint16_t><<<grid, 256, 0, stream>>>(Q, Kb, Vb, sinks, out);
  } else {
    attn_kernel<float><<<grid, 256, 0, stream>>>(Q, K, V, sinks, out);
  }
}